// Round 8
// baseline (263.998 us; speedup 1.0000x reference)
//
#include <hip/hip_runtime.h>
#include <stdint.h>

typedef unsigned short u16;
typedef __bf16 bf16x8 __attribute__((ext_vector_type(8)));
typedef float f32x16 __attribute__((ext_vector_type(16)));

typedef const __attribute__((address_space(1))) void* gptr_t;
typedef __attribute__((address_space(3))) void* sptr_t;

// ---- sizes ----
// x: (32,256,56,56) f32, W: (256,256,3,3) f32, out: (32,256,28,28) f32
#define M_TOTAL    100352          // 32*56*56
#define WPACK_OFF  55115776L       // xp = 32*58*58*256 * 2 bytes
#define Y_OFF      56295424L       // + 9*256*256*2 = 1179648
#define STATS_OFF  107675648L      // + 32*56*56*256*2 = 51380224

__device__ __forceinline__ u16 f32_bf16(float f) {
  uint32_t u = __float_as_uint(f);
  u += 0x7FFFu + ((u >> 16) & 1u);
  return (u16)(u >> 16);
}
__device__ __forceinline__ float bf16_f32(u16 h) {
  return __uint_as_float(((uint32_t)h) << 16);
}
__device__ __forceinline__ void gload_lds16(const void* g, void* l) {
  __builtin_amdgcn_global_load_lds((gptr_t)g, (sptr_t)l, 16, 0, 0);
}

// ---- binarize + pack W:  wp[((f*32+cg)*256 + co)*8 + e] = sign(W[co][ci][kh][kw])
__global__ void prep_w(const float* __restrict__ W, u16* __restrict__ wp) {
  int idx = blockIdx.x * 256 + threadIdx.x;       // 0..589823
  int e  = idx & 7;
  int co = (idx >> 3) & 255;
  int ks = idx >> 11;                             // f*32 + cg
  int f  = ks >> 5;
  int ci = ((ks & 31) << 3) | e;
  int kh = (f * 11) >> 5;                         // f/3 for f in 0..8
  int kw = f - kh * 3;
  float v = W[((co * 256 + ci) * 3 + kh) * 3 + kw];
  wp[idx] = (u16)(0x3F80u | ((__float_as_uint(v) >> 16) & 0x8000u));
}

// ---- zero only the padded border of x_pad (228 border positions per image)
__global__ void border_zero(u16* __restrict__ xp) {
  int idx = blockIdx.x * 256 + threadIdx.x;       // 32*228*32 = 233472
  int c8 = idx & 31;
  int p  = (idx >> 5) % 228;
  int n  = (idx >> 5) / 228;
  int h, w;
  if (p < 58)       { h = 0;  w = p; }
  else if (p < 116) { h = 57; w = p - 58; }
  else { int q = p - 116; h = 1 + (q >> 1); w = 57 * (q & 1); }
  uint4* dst = (uint4*)(xp + (((long)n * 58 + h) * 58 + w) * 256 + c8 * 8);
  *dst = make_uint4(0, 0, 0, 0);
}

// ---- NCHW f32 -> padded NHWC bf16  (interior only; border zeroed by border_zero)
__global__ void prep_x(const float* __restrict__ x, u16* __restrict__ xp) {
  int b = blockIdx.x;                 // (n*56 + h)*4 + cblk
  int cblk = b & 3;
  int nh = b >> 2;
  int h = nh % 56, n = nh / 56;
  __shared__ float tile[64][57];
  int tid = threadIdx.x;
  const float* src = x + (((long)n * 256 + cblk * 64) * 56 + h) * 56;
#pragma unroll
  for (int i = 0; i < 14; ++i) {
    int idx = i * 256 + tid;          // 0..3583
    int c = idx / 56, wq = idx - c * 56;
    tile[c][wq] = src[(long)c * 3136 + wq];
  }
  __syncthreads();
  u16* dst = xp + (((long)n * 58 + (h + 1)) * 58 + 1) * 256 + cblk * 64;
#pragma unroll
  for (int i = 0; i < 14; ++i) {
    int idx = i * 256 + tid;
    int c = idx & 63, wq = idx >> 6;  // wq 0..55
    dst[(long)wq * 256 + c] = f32_bf16(tile[c][wq]);
  }
}

// ---- implicit-GEMM conv: BM=128, BN=128, 4 waves (wave tile 128x32),
//      A via LDS double-buffer (gload_lds), B direct global->register (L2-resident),
//      counted vmcnt(4), 3 blocks/CU (1568 blocks over 768 slots = 2.04 rounds).
__global__ __launch_bounds__(256, 3) void conv_gemm(
    const u16* __restrict__ xp, const u16* __restrict__ wp,
    u16* __restrict__ y, float* __restrict__ stats) {
  // A only: [buf(2)][kslot(4)][row(128)][8 bf16] -> gload_lds-linear, conflict-free
  __shared__ __align__(16) u16 As[2][4][128][8];   // 16 KB

  const int tid = threadIdx.x;
  const int w = tid >> 6, l = tid & 63;
  const int gm = blockIdx.x >> 1;                  // 784 M-tiles
  const int gn = blockIdx.x & 1;                   // 2 N-halves

  // ---- A staging: wave w, issue j -> chunk c=w+4j: kslot=j*2+(w>>1), rows (w&1)*64+l
  const int gr = gm * 128 + ((w & 1) << 6) + l;
  const int n   = gr / 3136;
  const int rem = gr - n * 3136;
  const int hh  = rem / 56;
  const int wx  = rem - hh * 56;
  const u16* gA = xp + (((long)n * 58 + hh) * 58 + wx) * 256 + ((w >> 1) << 3);
  u16* ldsA0 = &As[0][0][0][0] + w * 512;          // + buf*4096 + j*2048 (u16)

  auto stageA = [&](int t) {                       // t = K-half, 0..71; buf = t&1
    const int f = t >> 3;
    const int kh = (f * 11) >> 5;
    const int kw = f - kh * 3;
    const u16* ga = gA + (kh * 58 + kw) * 256 + (t & 7) * 32;
    u16* la = ldsA0 + (t & 1) * 4096;
    gload_lds16(ga,      la);                      // kslot (w>>1)
    gload_lds16(ga + 16, la + 2048);               // kslot 2+(w>>1)
  };

  // ---- fragment coords
  const int l31 = l & 31, lh = l >> 5;

  // ---- B register path: lane co = gn*128 + w*32 + l31, k-group lh; idx = kc
  const u16* gBr = wp + ((long)lh * 256 + gn * 128 + (w << 5) + l31) * 8;
  bf16x8 bc[2], bn_[2];

#define LOADB(T, DST)                                                     \
  {                                                                       \
    const u16* gb = gBr + (long)(T) * 8192;                               \
    DST[0] = *(const bf16x8*)(gb);                 /* kc0 */              \
    DST[1] = *(const bf16x8*)(gb + 4096);          /* kc1 */              \
  }

  f32x16 acc[4] = {};

  // prologue: half 0 in flight
  stageA(0);
  LOADB(0, bc);

#define BODY(H, CUR, NXT)                                                 \
  {                                                                       \
    if ((H) + 1 < 72) {                                                   \
      stageA((H) + 1);                                                    \
      LOADB((H) + 1, NXT);                                                \
      asm volatile("s_waitcnt vmcnt(4)" ::: "memory");                    \
    } else {                                                              \
      asm volatile("s_waitcnt vmcnt(0)" ::: "memory");                    \
    }                                                                     \
    __builtin_amdgcn_s_barrier();                                         \
    asm volatile("" ::: "memory");                                        \
    __builtin_amdgcn_s_setprio(1);                                        \
    _Pragma("unroll")                                                     \
    for (int kc = 0; kc < 2; ++kc) {                                      \
      bf16x8 av0 = *(const bf16x8*)&As[(H) & 1][kc * 2 + lh][ 0 + l31][0]; \
      bf16x8 av1 = *(const bf16x8*)&As[(H) & 1][kc * 2 + lh][32 + l31][0]; \
      bf16x8 av2 = *(const bf16x8*)&As[(H) & 1][kc * 2 + lh][64 + l31][0]; \
      bf16x8 av3 = *(const bf16x8*)&As[(H) & 1][kc * 2 + lh][96 + l31][0]; \
      acc[0] = __builtin_amdgcn_mfma_f32_32x32x16_bf16(av0, CUR[kc], acc[0], 0, 0, 0); \
      acc[1] = __builtin_amdgcn_mfma_f32_32x32x16_bf16(av1, CUR[kc], acc[1], 0, 0, 0); \
      acc[2] = __builtin_amdgcn_mfma_f32_32x32x16_bf16(av2, CUR[kc], acc[2], 0, 0, 0); \
      acc[3] = __builtin_amdgcn_mfma_f32_32x32x16_bf16(av3, CUR[kc], acc[3], 0, 0, 0); \
    }                                                                     \
    __builtin_amdgcn_s_setprio(0);                                        \
    asm volatile("s_waitcnt lgkmcnt(0)" ::: "memory");                    \
    __builtin_amdgcn_s_barrier();                                         \
    asm volatile("" ::: "memory");                                        \
  }

  for (int i = 0; i < 36; ++i) {
    const int h = i * 2;
    BODY(h,     bc,  bn_);
    BODY(h + 1, bn_, bc);
  }
#undef BODY
#undef LOADB

  // ---- per-channel partial sums -> atomics (C col = lane&31; lane, lane+32 same col)
  {
    float s = 0.f, q = 0.f;
#pragma unroll
    for (int rb = 0; rb < 4; ++rb)
#pragma unroll
      for (int j = 0; j < 16; ++j) {
        float v = acc[rb][j];
        s += v; q += v * v;
      }
    s += __shfl_xor(s, 32, 64);
    q += __shfl_xor(q, 32, 64);
    if (lh == 0) {
      int col = gn * 128 + (w << 5) + l31;
      atomicAdd(&stats[col], s);
      atomicAdd(&stats[256 + col], q);
    }
  }

  // ---- store y bf16: row = (reg&3) + 8*(reg>>2) + 4*lh, col = lane&31
  const long rbase = (long)gm * 128;
  const int  cbase = gn * 128 + (w << 5) + l31;
#pragma unroll
  for (int rb = 0; rb < 4; ++rb)
#pragma unroll
    for (int j = 0; j < 16; ++j) {
      long rr = rbase + rb * 32 + (j & 3) + 8 * (j >> 2) + 4 * lh;
      y[rr * 256 + cbase] = f32_bf16(acc[rb][j]);
    }
}

// ---- finalize BN coefficients: scale = gamma*rsqrt(var+eps), shift = beta - mean*scale
__global__ void bn_stats(const float* __restrict__ stats, const float* __restrict__ gamma,
                         const float* __restrict__ beta, float* __restrict__ sc) {
  int c = threadIdx.x;
  const float inv = 1.0f / (float)M_TOTAL;
  float mean = stats[c] * inv;
  float var  = stats[256 + c] * inv - mean * mean;
  float s = gamma[c] * rsqrtf(var + 1e-5f);
  float b = beta[c] - mean * s;
  sc[c] = s;
  sc[256 + c] = b;
}

// ---- fused BN + ReLU + 2x2 maxpool, NHWC bf16 -> NCHW f32 ----
__global__ void bn_pool(const u16* __restrict__ y, const float* __restrict__ sc,
                        float* __restrict__ out) {
  int b = blockIdx.x;                 // n*28 + ho
  int ho = b % 28, n = b / 28;
  __shared__ u16 t[256][113];         // [co][h2*56+wq], pad to break conflicts
  __shared__ float ssc[256], ssb[256];
  int tid = threadIdx.x;
  ssc[tid] = sc[tid];
  ssb[tid] = sc[256 + tid];
  const u16* src = y + (((long)n * 56 + ho * 2) * 56) * 256;
#pragma unroll
  for (int i = 0; i < 14; ++i) {
    int v = i * 256 + tid;            // vec idx over (h2,wq,co/8): 3584 vecs
    int cv = v & 31, hw = v >> 5;     // hw = h2*56+wq in 0..111
    union { uint4 u; u16 h[8]; } d;
    d.u = *(const uint4*)(src + (long)hw * 256 + cv * 8);
#pragma unroll
    for (int e = 0; e < 8; ++e) t[cv * 8 + e][hw] = d.h[e];
  }
  __syncthreads();
  float* dst = out + (long)n * 200704 + ho * 28;   // + co*784 + wo
#pragma unroll
  for (int i = 0; i < 28; ++i) {
    int oidx = i * 256 + tid;         // 0..7167
    int co = oidx / 28, wo = oidx - co * 28;
    float s = ssc[co], bb = ssb[co];
    int w0 = wo * 2;
    float r0 = fmaxf(s * bf16_f32(t[co][w0])      + bb, 0.f);
    float r1 = fmaxf(s * bf16_f32(t[co][w0 + 1])  + bb, 0.f);
    float r2 = fmaxf(s * bf16_f32(t[co][56 + w0]) + bb, 0.f);
    float r3 = fmaxf(s * bf16_f32(t[co][57 + w0]) + bb, 0.f);
    dst[(long)co * 784 + wo] = fmaxf(fmaxf(r0, r1), fmaxf(r2, r3));
  }
}

extern "C" void kernel_launch(void* const* d_in, const int* in_sizes, int n_in,
                              void* d_out, int out_size, void* d_ws, size_t ws_size,
                              hipStream_t stream) {
  const float* x     = (const float*)d_in[0];
  const float* W     = (const float*)d_in[1];
  const float* gamma = (const float*)d_in[2];
  const float* beta  = (const float*)d_in[3];
  float* out = (float*)d_out;
  char* ws = (char*)d_ws;
  u16*  xp    = (u16*)ws;
  u16*  wp    = (u16*)(ws + WPACK_OFF);
  u16*  yb    = (u16*)(ws + Y_OFF);
  float* stats = (float*)(ws + STATS_OFF);   // sum[256], sumsq[256], scale[256], shift[256]

  hipMemsetAsync(stats, 0, 512 * sizeof(float), stream);
  hipLaunchKernelGGL(border_zero, dim3(912), dim3(256), 0, stream, xp);
  hipLaunchKernelGGL(prep_w, dim3(2304), dim3(256), 0, stream, W, wp);
  hipLaunchKernelGGL(prep_x, dim3(32 * 56 * 4), dim3(256), 0, stream, x, xp);
  hipLaunchKernelGGL(conv_gemm, dim3(1568), dim3(256), 0, stream, xp, wp, yb, stats);
  hipLaunchKernelGGL(bn_stats, dim3(1), dim3(256), 0, stream, stats, gamma, beta, stats + 512);
  hipLaunchKernelGGL(bn_pool, dim3(32 * 28), dim3(256), 0, stream, yb, stats + 512, out);
}

// Round 10
// 216.043 us; speedup vs baseline: 1.2220x; 1.2220x over previous
//
#include <hip/hip_runtime.h>
#include <stdint.h>

typedef unsigned short u16;
typedef __bf16 bf16x8 __attribute__((ext_vector_type(8)));
typedef float f32x16 __attribute__((ext_vector_type(16)));

// ---- sizes ----
// x: (32,256,56,56) f32, W: (256,256,3,3) f32, out: (32,256,28,28) f32
#define M_TOTAL    100352          // 32*56*56
#define PLANE_U16  861184L         // one 8-ch plane: 32*58*58 rows * 8 u16
#define WPACK_OFF  55115776L       // xp2 = 32 planes * 861184 * 2B
#define Y_OFF      56295424L       // + 9*256*256*2 = 1179648
#define STATS_OFF  107675648L      // + 32*56*56*256*2 = 51380224

__device__ __forceinline__ u16 f32_bf16(float f) {
  uint32_t u = __float_as_uint(f);
  u += 0x7FFFu + ((u >> 16) & 1u);
  return (u16)(u >> 16);
}
__device__ __forceinline__ float bf16_f32(u16 h) {
  return __uint_as_float(((uint32_t)h) << 16);
}

// ---- binarize + pack W:  wp[((f*32+cg)*256 + co)*8 + e] = sign(W[co][ci][kh][kw])
__global__ void prep_w(const float* __restrict__ W, u16* __restrict__ wp) {
  int idx = blockIdx.x * 256 + threadIdx.x;       // 0..589823
  int e  = idx & 7;
  int co = (idx >> 3) & 255;
  int ks = idx >> 11;                             // f*32 + cg
  int f  = ks >> 5;
  int ci = ((ks & 31) << 3) | e;
  int kh = (f * 11) >> 5;                         // f/3 for f in 0..8
  int kw = f - kh * 3;
  float v = W[((co * 256 + ci) * 3 + kh) * 3 + kw];
  wp[idx] = (u16)(0x3F80u | ((__float_as_uint(v) >> 16) & 0x8000u));
}

// ---- zero only the padded border rows of xp2 (all 32 planes)
__global__ void border_zero(u16* __restrict__ xp2) {
  int idx = blockIdx.x * 256 + threadIdx.x;       // 32n*228p*32g = 233472
  int g = idx & 31;
  int p = (idx >> 5) % 228;
  int n = (idx >> 5) / 228;
  int h, w;
  if (p < 58)       { h = 0;  w = p; }
  else if (p < 116) { h = 57; w = p - 58; }
  else { int q = p - 116; h = 1 + (q >> 1); w = 57 * (q & 1); }
  long r = ((long)n * 58 + h) * 58 + w;
  *(uint4*)(xp2 + g * PLANE_U16 + r * 8) = make_uint4(0, 0, 0, 0);
}

// ---- NCHW f32 -> channel-plane bf16: xp2[c/8][padded row][c&7]
__global__ void prep_x(const float* __restrict__ x, u16* __restrict__ xp2) {
  int b = blockIdx.x;                 // (n*56 + h)*4 + cblk
  int cblk = b & 3;
  int nh = b >> 2;
  int h = nh % 56, n = nh / 56;
  __shared__ float tile[64][57];
  int tid = threadIdx.x;
  const float* src = x + (((long)n * 256 + cblk * 64) * 56 + h) * 56;
#pragma unroll
  for (int i = 0; i < 14; ++i) {
    int idx = i * 256 + tid;          // 0..3583
    int c = idx / 56, wq = idx - c * 56;
    tile[c][wq] = src[(long)c * 3136 + wq];
  }
  __syncthreads();
  u16* base = xp2 + (long)(cblk * 8) * PLANE_U16 + (((long)n * 58 + h + 1) * 58 + 1) * 8;
#pragma unroll
  for (int i = 0; i < 2; ++i) {
    int idx = i * 256 + tid;          // 448 items: w(56) x g(8)
    if (idx < 448) {
      int wq = idx >> 3, g = idx & 7;
      union { uint4 u; u16 hx[8]; } d;
#pragma unroll
      for (int e = 0; e < 8; ++e) d.hx[e] = f32_bf16(tile[g * 8 + e][wq]);
      *(uint4*)(base + (long)g * PLANE_U16 + wq * 8) = d.u;
    }
  }
}

// ---- implicit-GEMM conv: LDS-free, barrier-free. 4 independent waves/block,
//      wave tile 128x64, A and B double-buffered in registers, coalesced
//      global_load_dwordx4 from channel-plane layouts. 2 blocks/CU.
__global__ __launch_bounds__(256, 2) void conv_gemm(
    const u16* __restrict__ xp2, const u16* __restrict__ wp,
    u16* __restrict__ y, float* __restrict__ stats) {
  const int tid = threadIdx.x;
  const int w = tid >> 6, l = tid & 63;
  const int gm = blockIdx.x;                       // 784 M-tiles
  const int l31 = l & 31, lh = l >> 5;

  // per-lane A offsets (u16 units): plane-half lh + padded row (per rb)
  long voffA0, voffA1, voffA2, voffA3;
  {
    long vs[4];
#pragma unroll
    for (int rb = 0; rb < 4; ++rb) {
      int gr = gm * 128 + rb * 32 + l31;
      int n = gr / 3136, rem = gr - n * 3136;
      int hh = rem / 56, wx = rem - hh * 56;
      vs[rb] = (long)lh * PLANE_U16 + (((long)n * 58 + hh) * 58 + wx) * 8;
    }
    voffA0 = vs[0]; voffA1 = vs[1]; voffA2 = vs[2]; voffA3 = vs[3];
  }
  const long voffB = (long)lh * 2048 + ((w << 6) + l31) * 8;

  bf16x8 aC[2][4], aN[2][4], bC[2][2], bN[2][2];   // [kc][rb] / [kc][cb]
  f32x16 acc[4][2] = {};

  // K-half T = f*8 + cc: tap f = T>>3 (row shift), channel chunk cc = T&7
  // planes for half T: cc*4 + kc*2 + lh  (lh folded into voffA)
#define LOADA(T, DST)                                                        \
  {                                                                          \
    const int f_ = (T) >> 3;                                                 \
    const int kh_ = (f_ * 11) >> 5;                                          \
    const int kw_ = f_ - kh_ * 3;                                            \
    const u16* ba = xp2 + (long)((T) & 7) * 4 * PLANE_U16                    \
                    + (kh_ * 58 + kw_) * 8;                                  \
    DST[0][0] = *(const bf16x8*)(ba + voffA0);                               \
    DST[0][1] = *(const bf16x8*)(ba + voffA1);                               \
    DST[0][2] = *(const bf16x8*)(ba + voffA2);                               \
    DST[0][3] = *(const bf16x8*)(ba + voffA3);                               \
    const u16* ba1 = ba + 2 * PLANE_U16;                                     \
    DST[1][0] = *(const bf16x8*)(ba1 + voffA0);                              \
    DST[1][1] = *(const bf16x8*)(ba1 + voffA1);                              \
    DST[1][2] = *(const bf16x8*)(ba1 + voffA2);                              \
    DST[1][3] = *(const bf16x8*)(ba1 + voffA3);                              \
  }
#define LOADB(T, DST)                                                        \
  {                                                                          \
    const u16* bb = wp + (long)((((T) >> 3) << 5) + (((T) & 7) << 2)) * 2048 \
                    + voffB;                                                 \
    DST[0][0] = *(const bf16x8*)(bb);                                        \
    DST[0][1] = *(const bf16x8*)(bb + 256);                                  \
    DST[1][0] = *(const bf16x8*)(bb + 4096);                                 \
    DST[1][1] = *(const bf16x8*)(bb + 4096 + 256);                           \
  }
#define MFMA8(A, B)                                                          \
  {                                                                          \
    _Pragma("unroll")                                                        \
    for (int kc = 0; kc < 2; ++kc)                                           \
      _Pragma("unroll")                                                      \
      for (int rb = 0; rb < 4; ++rb) {                                       \
        acc[rb][0] = __builtin_amdgcn_mfma_f32_32x32x16_bf16(                \
            A[kc][rb], B[kc][0], acc[rb][0], 0, 0, 0);                       \
        acc[rb][1] = __builtin_amdgcn_mfma_f32_32x32x16_bf16(                \
            A[kc][rb], B[kc][1], acc[rb][1], 0, 0, 0);                       \
      }                                                                      \
  }

  // prologue
  LOADA(0, aC);
  LOADB(0, bC);

  for (int i = 0; i < 36; ++i) {
    const int h = i * 2;
    if (h + 1 < 72) { LOADA(h + 1, aN); LOADB(h + 1, bN); }
    MFMA8(aC, bC);
    if (h + 2 < 72) { LOADA(h + 2, aC); LOADB(h + 2, bC); }
    MFMA8(aN, bN);
  }
#undef LOADA
#undef LOADB
#undef MFMA8

  // ---- per-channel partial sums -> atomics (C col = lane&31)
#pragma unroll
  for (int cb = 0; cb < 2; ++cb) {
    float s = 0.f, q = 0.f;
#pragma unroll
    for (int rb = 0; rb < 4; ++rb)
#pragma unroll
      for (int j = 0; j < 16; ++j) {
        float v = acc[rb][cb][j];
        s += v; q += v * v;
      }
    s += __shfl_xor(s, 32, 64);
    q += __shfl_xor(q, 32, 64);
    if (lh == 0) {
      int col = (w << 6) + cb * 32 + l31;
      atomicAdd(&stats[col], s);
      atomicAdd(&stats[256 + col], q);
    }
  }

  // ---- store y bf16: row = (reg&3) + 8*(reg>>2) + 4*lh, col = lane&31
  const long rbase = (long)gm * 128;
#pragma unroll
  for (int rb = 0; rb < 4; ++rb)
#pragma unroll
    for (int j = 0; j < 16; ++j) {
      long rr = rbase + rb * 32 + (j & 3) + 8 * (j >> 2) + 4 * lh;
      u16* dst = y + rr * 256 + (w << 6) + l31;
      dst[0]  = f32_bf16(acc[rb][0][j]);
      dst[32] = f32_bf16(acc[rb][1][j]);
    }
}

// ---- finalize BN coefficients: scale = gamma*rsqrt(var+eps), shift = beta - mean*scale
__global__ void bn_stats(const float* __restrict__ stats, const float* __restrict__ gamma,
                         const float* __restrict__ beta, float* __restrict__ sc) {
  int c = threadIdx.x;
  const float inv = 1.0f / (float)M_TOTAL;
  float mean = stats[c] * inv;
  float var  = stats[256 + c] * inv - mean * mean;
  float s = gamma[c] * rsqrtf(var + 1e-5f);
  float b = beta[c] - mean * s;
  sc[c] = s;
  sc[256 + c] = b;
}

// ---- fused BN + ReLU + 2x2 maxpool, NHWC bf16 -> NCHW f32 ----
__global__ void bn_pool(const u16* __restrict__ y, const float* __restrict__ sc,
                        float* __restrict__ out) {
  int b = blockIdx.x;                 // n*28 + ho
  int ho = b % 28, n = b / 28;
  __shared__ u16 t[256][113];         // [co][h2*56+wq], pad to break conflicts
  __shared__ float ssc[256], ssb[256];
  int tid = threadIdx.x;
  ssc[tid] = sc[tid];
  ssb[tid] = sc[256 + tid];
  const u16* src = y + (((long)n * 56 + ho * 2) * 56) * 256;
#pragma unroll
  for (int i = 0; i < 14; ++i) {
    int v = i * 256 + tid;            // vec idx over (h2,wq,co/8): 3584 vecs
    int cv = v & 31, hw = v >> 5;     // hw = h2*56+wq in 0..111
    union { uint4 u; u16 h[8]; } d;
    d.u = *(const uint4*)(src + (long)hw * 256 + cv * 8);
#pragma unroll
    for (int e = 0; e < 8; ++e) t[cv * 8 + e][hw] = d.h[e];
  }
  __syncthreads();
  float* dst = out + (long)n * 200704 + ho * 28;   // + co*784 + wo
#pragma unroll
  for (int i = 0; i < 28; ++i) {
    int oidx = i * 256 + tid;         // 0..7167
    int co = oidx / 28, wo = oidx - co * 28;
    float s = ssc[co], bb = ssb[co];
    int w0 = wo * 2;
    float r0 = fmaxf(s * bf16_f32(t[co][w0])      + bb, 0.f);
    float r1 = fmaxf(s * bf16_f32(t[co][w0 + 1])  + bb, 0.f);
    float r2 = fmaxf(s * bf16_f32(t[co][56 + w0]) + bb, 0.f);
    float r3 = fmaxf(s * bf16_f32(t[co][57 + w0]) + bb, 0.f);
    dst[(long)co * 784 + wo] = fmaxf(fmaxf(r0, r1), fmaxf(r2, r3));
  }
}

extern "C" void kernel_launch(void* const* d_in, const int* in_sizes, int n_in,
                              void* d_out, int out_size, void* d_ws, size_t ws_size,
                              hipStream_t stream) {
  const float* x     = (const float*)d_in[0];
  const float* W     = (const float*)d_in[1];
  const float* gamma = (const float*)d_in[2];
  const float* beta  = (const float*)d_in[3];
  float* out = (float*)d_out;
  char* ws = (char*)d_ws;
  u16*  xp2   = (u16*)ws;
  u16*  wp    = (u16*)(ws + WPACK_OFF);
  u16*  yb    = (u16*)(ws + Y_OFF);
  float* stats = (float*)(ws + STATS_OFF);   // sum[256], sumsq[256], scale[256], shift[256]

  hipMemsetAsync(stats, 0, 512 * sizeof(float), stream);
  hipLaunchKernelGGL(border_zero, dim3(912), dim3(256), 0, stream, xp2);
  hipLaunchKernelGGL(prep_w, dim3(2304), dim3(256), 0, stream, W, wp);
  hipLaunchKernelGGL(prep_x, dim3(32 * 56 * 4), dim3(256), 0, stream, x, xp2);
  hipLaunchKernelGGL(conv_gemm, dim3(784), dim3(256), 0, stream, xp2, wp, yb, stats);
  hipLaunchKernelGGL(bn_stats, dim3(1), dim3(256), 0, stream, stats, gamma, beta, stats + 512);
  hipLaunchKernelGGL(bn_pool, dim3(32 * 28), dim3(256), 0, stream, yb, stats + 512, out);
}